// Round 7
// baseline (8090.269 us; speedup 1.0000x reference)
//
#include <hip/hip_runtime.h>

typedef unsigned short u16;
typedef unsigned int u32;
typedef __attribute__((ext_vector_type(8))) unsigned short ushort8v;

__device__ __forceinline__ float bf2f(u16 u) { return __uint_as_float(((u32)u) << 16); }
__device__ __forceinline__ u16 f2bf(float f) {
    u32 u = __float_as_uint(f);
    u32 r = u + 0x7fffu + ((u >> 16) & 1u);
    return (u16)(r >> 16);
}
__device__ __forceinline__ float wave_sum(float v) {
    #pragma unroll
    for (int m = 1; m < 64; m <<= 1) v += __shfl_xor(v, m, 64);
    return v;
}
// dtype-flexible load/store: f32=true -> float32 buffer, else bf16 (u16) buffer
__device__ __forceinline__ float gld(const void* p, size_t i, bool f32) {
    return f32 ? ((const float*)p)[i] : bf2f(((const u16*)p)[i]);
}
__device__ __forceinline__ void gst(void* p, size_t i, bool f32, float v) {
    if (f32) ((float*)p)[i] = v;
    else     ((u16*)p)[i] = f2bf(v);
}
__device__ __forceinline__ void ldf8(const void* p, size_t i, bool f32, float* o) {
    if (f32) {
        const float4* q = (const float4*)((const float*)p + i);
        float4 a = q[0], b = q[1];
        o[0] = a.x; o[1] = a.y; o[2] = a.z; o[3] = a.w;
        o[4] = b.x; o[5] = b.y; o[6] = b.z; o[7] = b.w;
    } else {
        ushort8v v = *(const ushort8v*)((const u16*)p + i);
        #pragma unroll
        for (int j = 0; j < 8; j++) o[j] = bf2f(v[j]);
    }
}

// ---- dtype probe: bf16 N(0,1) decodes |v|<~5 always; f32 viewed as u16 halves
// has ~48% of low-half words decoding to |v|>64 or NaN -> flags within 1024 floats.
__global__ void __launch_bounds__(256) k_probe(const u16* __restrict__ x, u32* __restrict__ flag) {
    __shared__ int cnt;
    if (threadIdx.x == 0) cnt = 0;
    __syncthreads();
    int bad = 0;
    for (int i = threadIdx.x; i < 2048; i += 256) {
        float v = bf2f(x[i]);
        if (!(v > -64.f && v < 64.f)) bad = 1;
    }
    if (bad) atomicAdd(&cnt, 1);
    __syncthreads();
    if (threadIdx.x == 0) flag[0] = (cnt > 0) ? 1u : 0u;
}

__global__ void __launch_bounds__(256) k_zero(u32* __restrict__ p, int n) {
    int i = blockIdx.x * 256 + threadIdx.x;
    if (i < n) p[i] = 0u;
}

// ---- VALU f32 GEMM: C[m, col0+n] = sum_k A[arow0+m, k]*B[brow0+n, k], n < Nn
// 128x128 tile, 256 threads, 8x8 microtile, BK=16.
// amode/bmode: 1 = dtype follows probe flag; 0 = always bf16 (internal buffers)
// EPI: 0 = bf16 store; 1 = bf16 gelu(acc+bias[col]); 2 = f32 store
template <int EPI>
__global__ void __launch_bounds__(256) vgemm(const u32* __restrict__ dflag, int amode, int bmode,
                                             const void* __restrict__ A, const void* __restrict__ B,
                                             void* __restrict__ Cout, const void* __restrict__ bias,
                                             int M, int Nn, int K, int ldC, int col0, int brow0,
                                             int arow0) {
    bool ibf32 = dflag[0] != 0u;
    bool af32 = amode && ibf32;
    bool bf32 = bmode && ibf32;
    __shared__ float sA[128 * 17];
    __shared__ float sB[128 * 17];
    const int tid = threadIdx.x;
    const int m0 = blockIdx.y * 128;
    const int n0 = blockIdx.x * 128;
    const int ty = tid >> 4, tx = tid & 15;

    float acc[8][8];
    #pragma unroll
    for (int i = 0; i < 8; i++)
        #pragma unroll
        for (int j = 0; j < 8; j++) acc[i][j] = 0.f;

    const int r = tid >> 1, kk0 = (tid & 1) * 8;
    for (int k0 = 0; k0 < K; k0 += 16) {
        __syncthreads();
        {
            float a8[8] = {0, 0, 0, 0, 0, 0, 0, 0};
            if (m0 + r < M) ldf8(A, (size_t)(arow0 + m0 + r) * K + k0 + kk0, af32, a8);
            #pragma unroll
            for (int j = 0; j < 8; j++) sA[r * 17 + kk0 + j] = a8[j];
            float b8[8] = {0, 0, 0, 0, 0, 0, 0, 0};
            if (n0 + r < Nn) ldf8(B, (size_t)(brow0 + n0 + r) * K + k0 + kk0, bf32, b8);
            #pragma unroll
            for (int j = 0; j < 8; j++) sB[r * 17 + kk0 + j] = b8[j];
        }
        __syncthreads();
        #pragma unroll
        for (int kk = 0; kk < 16; kk++) {
            float ar[8], bc[8];
            #pragma unroll
            for (int i = 0; i < 8; i++) ar[i] = sA[(ty * 8 + i) * 17 + kk];
            #pragma unroll
            for (int j = 0; j < 8; j++) bc[j] = sB[(tx * 8 + j) * 17 + kk];
            #pragma unroll
            for (int i = 0; i < 8; i++)
                #pragma unroll
                for (int j = 0; j < 8; j++) acc[i][j] += ar[i] * bc[j];
        }
    }

    #pragma unroll
    for (int i = 0; i < 8; i++) {
        int gr = m0 + ty * 8 + i;
        if (gr >= M) continue;
        #pragma unroll
        for (int j = 0; j < 8; j++) {
            int cn = n0 + tx * 8 + j;
            if (cn >= Nn) continue;
            int col = col0 + cn;
            float v = acc[i][j];
            if (EPI == 1) {
                v += gld(bias, col, ibf32);
                v = 0.5f * v * (1.0f + erff(v * 0.70710678f));
                ((u16*)Cout)[(size_t)gr * ldC + col] = f2bf(v);
            } else if (EPI == 0) {
                ((u16*)Cout)[(size_t)gr * ldC + col] = f2bf(v);
            } else {
                ((float*)Cout)[(size_t)gr * ldC + col] = v;
            }
        }
    }
}

// ---- partial att dot from a 64-channel quarter (heads 2q, 2q+1 live fully inside quarter q)
// xq: [N,64] bf16 = (x@W^T) channels [q*64, q*64+64). For t in {0,1}, hl in {0,1}:
// th = t*8 + 2q + hl: dots[n*32 + off + th] = sum_{c<32} xq[n, hl*32+c] * att[th*32+c]
__global__ void __launch_bounds__(256) k_dq(const u32* __restrict__ dflag,
                                            const u16* __restrict__ xq, const void* __restrict__ att,
                                            u16* __restrict__ dots, int N, int q, int off) {
    bool f32 = dflag[0] != 0u;
    int id = blockIdx.x * 256 + threadIdx.x;   // n*4 + t*2 + hl
    int n = id >> 2;
    if (n >= N) return;
    int t = (id >> 1) & 1;
    int hl = id & 1;
    int th = t * 8 + q * 2 + hl;
    float s = 0.f;
    #pragma unroll 8
    for (int c = 0; c < 32; c++)
        s += bf2f(xq[(size_t)n * 64 + hl * 32 + c]) * gld(att, th * 32 + c, f32);
    dots[(size_t)n * 32 + off + th] = f2bf(s);
}

// ---- CSR build (dst-major) ----
__global__ void __launch_bounds__(256) k_count(const int* __restrict__ ei, u32* __restrict__ cnt, int E) {
    int e = blockIdx.x * 256 + threadIdx.x;
    if (e < E) atomicAdd(cnt + ei[E + e], 1u);
}
__global__ void __launch_bounds__(256) k_scanA(u32* __restrict__ buf, u32* __restrict__ bsum, int N) {
    int t = threadIdx.x, idx = blockIdx.x * 256 + t;
    u32 v = (idx < N) ? buf[idx] : 0u;
    __shared__ u32 sc[256];
    sc[t] = v; __syncthreads();
    for (int d = 1; d < 256; d <<= 1) {
        u32 add = (t >= d) ? sc[t - d] : 0u; __syncthreads();
        sc[t] += add; __syncthreads();
    }
    if (idx < N) buf[idx] = sc[t] - v;
    if (t == 255) bsum[blockIdx.x] = sc[255];
}
__global__ void __launch_bounds__(256) k_scanB(u32* __restrict__ bsum, int nb) {
    int t = threadIdx.x;
    u32 v = (t < nb) ? bsum[t] : 0u;
    __shared__ u32 sc[256];
    sc[t] = v; __syncthreads();
    for (int d = 1; d < 256; d <<= 1) {
        u32 add = (t >= d) ? sc[t - d] : 0u; __syncthreads();
        sc[t] += add; __syncthreads();
    }
    if (t < nb) bsum[t] = sc[t] - v;
}
__global__ void __launch_bounds__(256) k_scanC(u32* __restrict__ obuf, u32* __restrict__ cursor,
                                               const u32* __restrict__ bsum, int N, int E) {
    int idx = blockIdx.x * 256 + threadIdx.x;
    if (idx < N) {
        u32 o = obuf[idx] + bsum[blockIdx.x];
        obuf[idx] = o;
        cursor[idx] = o;
    }
    if (blockIdx.x == 0 && threadIdx.x == 0) obuf[N] = (u32)E;
}
__global__ void __launch_bounds__(256) k_scatter(const int* __restrict__ ei, u32* __restrict__ cursor,
                                                 u32* __restrict__ elist, int E) {
    int e = blockIdx.x * 256 + threadIdx.x;
    if (e >= E) return;
    u32 slot = atomicAdd(cursor + ei[E + e], 1u);
    elist[slot] = (u32)e;
}

// ---- fused per-node softmax aggregation over 64-channel window [ch0, ch0+64)
// one wave per node, lane owns 1 channel; writes v = agg + bias + x (pre-LN)
// into vout (dtype follows probe flag -> matches d_out dtype)
__global__ void __launch_bounds__(256) k_node(const u32* __restrict__ dflag,
                                              const int* __restrict__ ei, const int* __restrict__ et,
                                              const void* __restrict__ ew, const void* __restrict__ x,
                                              const u16* __restrict__ xq, const u16* __restrict__ dots,
                                              const u32* __restrict__ obuf, const u32* __restrict__ elist,
                                              const void* __restrict__ bias, void* __restrict__ vout,
                                              int N, int ch0) {
    bool f32 = dflag[0] != 0u;
    int node = blockIdx.x * 4 + (threadIdx.x >> 6);
    if (node >= N) return;
    int lane = threadIdx.x & 63;
    int ch = ch0 + lane;
    int hh = ch >> 5;
    float ad0 = bf2f(dots[(size_t)node * 32 + 16 + hh]);
    float ad1 = bf2f(dots[(size_t)node * 32 + 24 + hh]);
    // self-loop: type 0, weight 1
    float a = bf2f(dots[(size_t)node * 32 + hh]) + ad0;
    float p = __expf(a >= 0.f ? a : 0.2f * a);
    float den = p;
    float num = p * bf2f(xq[(size_t)node * 64 + lane]);
    u32 kbeg = obuf[node], kend = obuf[node + 1];
    for (u32 k = kbeg; k < kend; k++) {
        int e = (int)elist[k];
        int src = ei[e];
        int t = et[e];
        float w = gld(ew, e, f32);
        float aa = bf2f(dots[(size_t)src * 32 + t * 8 + hh]) + (t ? ad1 : ad0);
        float pp = __expf(aa >= 0.f ? aa : 0.2f * aa);
        den += pp;
        num += pp * w * bf2f(xq[(size_t)src * 64 + lane]);
    }
    float v = num / den + gld(bias, ch, f32) + gld(x, (size_t)node * 256 + ch, f32);
    gst(vout, (size_t)node * 256 + ch, f32, v);
}

// ---- LN1 in place on v ([N,256], dtype follows flag) -> h
__global__ void __launch_bounds__(256) k_ln1(const u32* __restrict__ dflag, void* __restrict__ v,
                                             const void* __restrict__ g, const void* __restrict__ b, int N) {
    bool f32 = dflag[0] != 0u;
    int node = blockIdx.x * 4 + (threadIdx.x >> 6);
    if (node >= N) return;
    int lane = threadIdx.x & 63;
    size_t base = (size_t)node * 256 + lane * 4;
    float v0 = gld(v, base + 0, f32), v1 = gld(v, base + 1, f32);
    float v2 = gld(v, base + 2, f32), v3 = gld(v, base + 3, f32);
    float mu = wave_sum(v0 + v1 + v2 + v3) * (1.f / 256.f);
    float d0 = v0 - mu, d1 = v1 - mu, d2 = v2 - mu, d3 = v3 - mu;
    float var = wave_sum(d0 * d0 + d1 * d1 + d2 * d2 + d3 * d3) * (1.f / 256.f);
    float rs = rsqrtf(var + 1e-5f);
    gst(v, base + 0, f32, d0 * rs * gld(g, lane * 4 + 0, f32) + gld(b, lane * 4 + 0, f32));
    gst(v, base + 1, f32, d1 * rs * gld(g, lane * 4 + 1, f32) + gld(b, lane * 4 + 1, f32));
    gst(v, base + 2, f32, d2 * rs * gld(g, lane * 4 + 2, f32) + gld(b, lane * 4 + 2, f32));
    gst(v, base + 3, f32, d3 * rs * gld(g, lane * 4 + 3, f32) + gld(b, lane * 4 + 3, f32));
}

// ---- residual + LN2 (chunked, in place on h rows [row0, row0+rows)): out = LN(h + ffn + fb2)
__global__ void __launch_bounds__(256) k_ln2(const u32* __restrict__ dflag,
                                             void* __restrict__ h, int row0, const float* __restrict__ ffn,
                                             const void* __restrict__ fb2, const void* __restrict__ g,
                                             const void* __restrict__ b, int rows) {
    bool f32 = dflag[0] != 0u;
    int row = blockIdx.x * 4 + (threadIdx.x >> 6);
    if (row >= rows) return;
    int lane = threadIdx.x & 63;
    size_t hbase = (size_t)(row0 + row) * 256 + lane * 4;
    size_t fbase = (size_t)row * 256 + lane * 4;
    float4 tv = *(const float4*)(ffn + fbase);
    float v0 = tv.x + gld(h, hbase + 0, f32) + gld(fb2, lane * 4 + 0, f32);
    float v1 = tv.y + gld(h, hbase + 1, f32) + gld(fb2, lane * 4 + 1, f32);
    float v2 = tv.z + gld(h, hbase + 2, f32) + gld(fb2, lane * 4 + 2, f32);
    float v3 = tv.w + gld(h, hbase + 3, f32) + gld(fb2, lane * 4 + 3, f32);
    float mu = wave_sum(v0 + v1 + v2 + v3) * (1.f / 256.f);
    float d0 = v0 - mu, d1 = v1 - mu, d2 = v2 - mu, d3 = v3 - mu;
    float var = wave_sum(d0 * d0 + d1 * d1 + d2 * d2 + d3 * d3) * (1.f / 256.f);
    float rs = rsqrtf(var + 1e-5f);
    gst(h, hbase + 0, f32, d0 * rs * gld(g, lane * 4 + 0, f32) + gld(b, lane * 4 + 0, f32));
    gst(h, hbase + 1, f32, d1 * rs * gld(g, lane * 4 + 1, f32) + gld(b, lane * 4 + 1, f32));
    gst(h, hbase + 2, f32, d2 * rs * gld(g, lane * 4 + 2, f32) + gld(b, lane * 4 + 2, f32));
    gst(h, hbase + 3, f32, d3 * rs * gld(g, lane * 4 + 3, f32) + gld(b, lane * 4 + 3, f32));
}

extern "C" void kernel_launch(void* const* d_in, const int* in_sizes, int n_in,
                              void* d_out, int out_size, void* d_ws, size_t ws_size,
                              hipStream_t stream) {
    const int N = in_sizes[0] / 256;     // 50000
    const int E = in_sizes[1] / 2;       // 800000
    const int NB = (N + 255) / 256;      // 196

    const void* x    = d_in[0];
    const int*  ei   = (const int*)d_in[1];
    const int*  et   = (const int*)d_in[2];
    const void* ew   = d_in[3];
    const void* Wsrc = d_in[4];
    const void* Wdst = d_in[5];
    const void* attS = d_in[6];
    const void* attD = d_in[7];
    const void* bias = d_in[8];
    const void* g1   = d_in[9];
    const void* b1   = d_in[10];
    const void* g2   = d_in[11];
    const void* b2   = d_in[12];
    const void* W1   = d_in[13];
    const void* fb1  = d_in[14];
    const void* W2   = d_in[15];
    const void* fb2  = d_in[16];

    // single fixed layout, total ~14.5 MB
    char* ws = (char*)d_ws;
    u32* flag   = (u32*)(ws + 0);            // 256 B
    u32* bsum   = (u32*)(ws + 256);          // 1 KB
    u32* obuf   = (u32*)(ws + 1536);         // (N+1)*4 ~ 200 KB
    u32* cursor = (u32*)(ws + 201984);       // N*4 = 200 KB
    u16* dots   = (u16*)(ws + 402176);       // N*32*2 = 3.2 MB
    u32* elist  = (u32*)(ws + 3602176);      // E*4 = 3.2 MB
    char* region = ws + 6802176;             // 7.68 MB shared region
    u16*   xq     = (u16*)region;                    // [N,64] bf16 = 6.4 MB
    u16*   act    = (u16*)region;                    // FFN: [2500,1024] bf16 = 5.12 MB
    float* ffnout = (float*)(region + 5120000);      // FFN: [2500,256] f32 = 2.56 MB
    void*  hbuf   = d_out;                   // v -> h -> out staged in d_out (dtype = flag)

    k_probe<<<1, 256, 0, stream>>>((const u16*)x, flag);

    const int gyN = (N + 127) / 128;
    const int dqg = (N * 4 + 255) / 256;

    // Phase A: attention dots, literal dataflow, per 64-channel quarter
    for (int q = 0; q < 4; q++) {
        vgemm<0><<<dim3(1, gyN), 256, 0, stream>>>(
            flag, 1, 1, x, Wsrc, xq, nullptr, N, 64, 256, 64, 0, q * 64, 0);
        k_dq<<<dqg, 256, 0, stream>>>(flag, xq, attS, dots, N, q, 0);
    }
    for (int q = 0; q < 4; q++) {
        vgemm<0><<<dim3(1, gyN), 256, 0, stream>>>(
            flag, 1, 1, x, Wdst, xq, nullptr, N, 64, 256, 64, 0, q * 64, 0);
        k_dq<<<dqg, 256, 0, stream>>>(flag, xq, attD, dots, N, q, 16);
    }

    // CSR build
    k_zero<<<NB, 256, 0, stream>>>(obuf, N);
    k_count<<<(E + 255) / 256, 256, 0, stream>>>(ei, obuf, E);
    k_scanA<<<NB, 256, 0, stream>>>(obuf, bsum, N);
    k_scanB<<<1, 256, 0, stream>>>(bsum, NB);
    k_scanC<<<NB, 256, 0, stream>>>(obuf, cursor, bsum, N, E);
    k_scatter<<<(E + 255) / 256, 256, 0, stream>>>(ei, cursor, elist, E);

    // Phase B: aggregation per 64-channel quarter (xq = x_src quarter)
    for (int q = 0; q < 4; q++) {
        vgemm<0><<<dim3(1, gyN), 256, 0, stream>>>(
            flag, 1, 1, x, Wsrc, xq, nullptr, N, 64, 256, 64, 0, q * 64, 0);
        k_node<<<(N + 3) / 4, 256, 0, stream>>>(flag, ei, et, ew, x, xq, dots,
                                                obuf, elist, bias, hbuf, N, q * 64);
    }
    k_ln1<<<(N + 3) / 4, 256, 0, stream>>>(flag, hbuf, g1, b1, N);

    // FFN + LN2, 20 chunks of 2500 rows (h rows addressed via arow0/row0, dtype-safe)
    const int rc = 2500;
    const int gyc = (rc + 127) / 128;
    for (int c = 0; c < N / rc; c++) {
        int r0 = c * rc;
        vgemm<1><<<dim3(8, gyc), 256, 0, stream>>>(flag, 1, 1,
            hbuf, W1, act, fb1, rc, 1024, 256, 1024, 0, 0, r0);
        vgemm<2><<<dim3(2, gyc), 256, 0, stream>>>(flag, 0, 1,
            act, W2, ffnout, nullptr, rc, 256, 1024, 256, 0, 0, 0);
        k_ln2<<<(rc + 3) / 4, 256, 0, stream>>>(flag, hbuf, r0, ffnout,
                                                fb2, g2, b2, rc);
    }
}